// Round 1
// 712.432 us; speedup vs baseline: 1.1298x; 1.1298x over previous
//
#include <hip/hip_runtime.h>
#include <cstdint>
#include <cstddef>

#define NEXP 7
#define EMBED_DIM 16
#define FOURH 1024
#define TWOH 512
#define HID 256
#define S_MAX 16641
#define D_IN (S_MAX + EMBED_DIM)
#define BATCH 1024
#define MTILE 192
#define MROWS 384  // 2 m-tiles of insurance capacity per expert

__constant__ int d_SIZES[NEXP] = {9, 25, 81, 289, 1089, 4225, 16641};
__constant__ int d_KPAD[NEXP] = {64, 64, 128, 320, 1152, 4288, 16704};
__constant__ int d_AOFF[NEXP] = {0, 64, 128, 256, 576, 1728, 6016};  // cum KPAD
// ceil(KPAD/512) = {1,1,1,1,3,9,33}; prefix:
__constant__ int d_KCOFF[NEXP + 1] = {0, 1, 2, 3, 4, 7, 16, 49};

typedef short bf16x8 __attribute__((ext_vector_type(8)));
typedef float f32x4 __attribute__((ext_vector_type(4)));

__device__ __forceinline__ float lrelu(float x) { return x > 0.f ? x : 0.2f * x; }

__device__ __forceinline__ unsigned short f2bf(float x) {
  union { float f; unsigned u; } v;
  v.f = x;
  unsigned r = v.u + 0x7FFFu + ((v.u >> 16) & 1u);  // RNE
  return (unsigned short)(r >> 16);
}

// ---------------- fused: bucket samples (block 0) + per-expert embed/bias init
// (blocks 1..7). Both roles independent; fusion removes one serialized launch.
__global__ __launch_bounds__(1024) void prep_kernel(
    const int* __restrict__ orders, int* __restrict__ counts,
    int* __restrict__ bases, int* __restrict__ list,
    const float* __restrict__ embed, const float* __restrict__ W_in,
    const float* __restrict__ b_in, float* __restrict__ hinit) {
  __shared__ int c[NEXP], p[NEXP];
  int t = threadIdx.x;
  if (blockIdx.x == 0) {
    // ---- bucket ----
    if (t < NEXP) c[t] = 0;
    __syncthreads();
    int o = orders[t];
    atomicAdd(&c[o], 1);
    __syncthreads();
    if (t == 0) {
      int s = 0;
      for (int i = 0; i < NEXP; ++i) { p[i] = s; s += c[i]; }
    }
    __syncthreads();
    if (t < NEXP) { counts[t] = c[t]; bases[t] = p[t]; }
    __syncthreads();
    int pos = atomicAdd(&p[o], 1);
    list[pos] = t;
  } else {
    // ---- hinit: hinit[o][j] = b_in[o][j] + embed[o] . W_in[o][S_MAX:][j] ----
    int o = blockIdx.x - 1;
    float a = b_in[o * FOURH + t];
    const float* wr = W_in + (size_t)o * D_IN * FOURH + (size_t)S_MAX * FOURH + t;
#pragma unroll
    for (int e = 0; e < EMBED_DIM; ++e)
      a = fmaf(embed[o * EMBED_DIM + e], wr[(size_t)e * FOURH], a);
    hinit[o * FOURH + t] = a;
  }
}

// ---------------- fused: gather+convert mazes into bucketed padded Ab (blocks
// [0, NEXP*MROWS)) + broadcast hinit into h by order (blocks [NEXP*MROWS, +1024))
__global__ __launch_bounds__(256) void gather_hb_kernel(
    const float* __restrict__ mazes, const int* __restrict__ counts,
    const int* __restrict__ bases, const int* __restrict__ list,
    unsigned short* __restrict__ Ab, const int* __restrict__ orders,
    const float* __restrict__ hinit, float* __restrict__ h) {
  int bx = blockIdx.x;
  if (bx >= NEXP * MROWS) {
    // ---- h broadcast ----
    int b = bx - NEXP * MROWS;
    int o = orders[b];
    const float4* src = (const float4*)(hinit + (size_t)o * FOURH);
    float4* dst = (float4*)(h + (size_t)b * FOURH);
    dst[threadIdx.x] = src[threadIdx.x];
    return;
  }
  // ---- gather ----
  int o = bx / MROWS;
  int m = bx % MROWS;
  int n = counts[o];
  int so = d_SIZES[o];
  int Kp = d_KPAD[o];
  const float* src = nullptr;
  if (m < n) src = mazes + (size_t)list[bases[o] + m] * S_MAX;
  unsigned short* dst = Ab + (size_t)d_AOFF[o] * MROWS + (size_t)m * Kp;
  int nk8 = Kp >> 3;
  for (int k8 = threadIdx.x; k8 < nk8; k8 += 256) {
    int k = k8 * 8;
    union { unsigned short u[8]; uint4 v; } pk;
#pragma unroll
    for (int e = 0; e < 8; ++e) {
      float val = (src && (k + e) < so) ? src[k + e] : 0.f;
      pk.u[e] = f2bf(val);
    }
    *(uint4*)(dst + k) = pk.v;
  }
}

// ---------------- layer-in grouped GEMM via bf16 MFMA ----------------
// grid: x = 49 (o,kc) chunk instances, y = 8 n-tiles of 128, z = 2 m-tiles of 192.
// block: 256 thr = 4 waves; wave w covers cols [y*128 + w*32, +32) as 2 n-subtiles.
__global__ __launch_bounds__(256, 2) void layerin_mfma(
    const unsigned short* __restrict__ Ab, const float* __restrict__ W_in,
    const int* __restrict__ counts, const int* __restrict__ bases,
    const int* __restrict__ list, float* __restrict__ h) {
  int bx = blockIdx.x;
  int o = 0;
#pragma unroll
  for (int t = 1; t < NEXP; ++t)
    if (bx >= d_KCOFF[t]) o = t;
  int kc = bx - d_KCOFF[o];
  int n = counts[o];
  int m_base = blockIdx.z * MTILE;
  if (m_base >= n) return;  // insurance tile unused almost always

  __shared__ unsigned short sA[8 * 194 * 8];  // [kg][m pad 194][8] bf16
  __shared__ int sid[MTILE];

  int tid = threadIdx.x;
  int wave = tid >> 6, lane = tid & 63;
  int q = lane >> 4, l16 = lane & 15;

  if (tid < MTILE) sid[tid] = (m_base + tid < n) ? list[bases[o] + m_base + tid] : 0;

  int so = d_SIZES[o];
  int Kp = d_KPAD[o];
  int klo = kc * 512;
  int klen = min(512, Kp - klo);  // multiple of 64

  int n0 = blockIdx.y * 128 + wave * 32;
  const float* Wc = W_in + (size_t)o * D_IN * FOURH + n0 + l16;
  const unsigned short* Abase =
      Ab + (size_t)d_AOFF[o] * MROWS + (size_t)m_base * Kp + klo;

  f32x4 acc[12][2];
#pragma unroll
  for (int mt = 0; mt < 12; ++mt) {
    acc[mt][0] = (f32x4)0.f;
    acc[mt][1] = (f32x4)0.f;
  }

  int kg = tid & 7;        // stage: k-group
  int mrow = tid >> 3;     // stage: row within round (32 rows/round)

  for (int ks = 0; ks < klen; ks += 64) {
    __syncthreads();
#pragma unroll
    for (int r = 0; r < 6; ++r) {
      int m = r * 32 + mrow;
      uint4 v = *(const uint4*)(Abase + (size_t)m * Kp + ks + kg * 8);
      *(uint4*)&sA[((kg * 194 + m) << 3)] = v;
    }
    __syncthreads();
#pragma unroll
    for (int st = 0; st < 2; ++st) {
      int kb = klo + ks + st * 32 + q * 8;
      bf16x8 bf0, bf1;
#pragma unroll
      for (int j = 0; j < 8; ++j) {
        int kj = kb + j;
        if (kj >= so) kj = so - 1;  // A is zero there; clamp keeps loads in-bounds
        float w0 = Wc[(size_t)kj * FOURH];
        float w1 = Wc[(size_t)kj * FOURH + 16];
        bf0[j] = (short)f2bf(w0);
        bf1[j] = (short)f2bf(w1);
      }
#pragma unroll
      for (int mt = 0; mt < 12; ++mt) {
        bf16x8 af = *(const bf16x8*)&sA[(((st * 4 + q) * 194 + mt * 16 + l16) << 3)];
        acc[mt][0] = __builtin_amdgcn_mfma_f32_16x16x32_bf16(af, bf0, acc[mt][0], 0, 0, 0);
        acc[mt][1] = __builtin_amdgcn_mfma_f32_16x16x32_bf16(af, bf1, acc[mt][1], 0, 0, 0);
      }
    }
  }

  int colA = n0 + l16, colB = n0 + 16 + l16;
#pragma unroll
  for (int mt = 0; mt < 12; ++mt) {
#pragma unroll
    for (int r = 0; r < 4; ++r) {
      int m = mt * 16 + q * 4 + r;
      if (m_base + m < n) {
        int s = sid[m];
        atomicAdd(&h[(size_t)s * FOURH + colA], acc[mt][0][r]);
        atomicAdd(&h[(size_t)s * FOURH + colB], acc[mt][1][r]);
      }
    }
  }
}

// ---------------- mlp1: z1 = lrelu( lrelu(h) @ W1 + b1 ) ----------------
// grid (2, 128), 256 thr. Block: cols [bx*256,+256), rows [by*8,+8).
// Thread: jt = tid&127 -> 2 consecutive cols (float2 W loads);
//         rg = tid>>7  -> 4 rows. 2 cols/thread halves LDS broadcast traffic
//         (old kernel was LDS-bound: 4 B/lane-FMA vs 1 B/lane-FMA balance).
__global__ __launch_bounds__(256) void mlp1_kernel(
    const float* __restrict__ X, const float* __restrict__ W,
    const float* __restrict__ b, float* __restrict__ Y) {
  constexpr int KD = FOURH, JD = TWOH, KT2 = 256;
  __shared__ float sh[8][KT2];
  int tid = threadIdx.x;
  int jt = tid & 127, rg = tid >> 7;
  int j0 = blockIdx.x * 256 + jt * 2;
  int m0 = blockIdx.y * 8;
  int srow = tid >> 5, su = tid & 31;
  const float* xp = X + (size_t)(m0 + srow) * KD;
  float acc[4][2];
#pragma unroll
  for (int i = 0; i < 4; ++i) { acc[i][0] = 0.f; acc[i][1] = 0.f; }
  for (int kb0 = 0; kb0 < KD; kb0 += KT2) {
    __syncthreads();
#pragma unroll
    for (int c = 0; c < 2; ++c) {
      int kl = c * 128 + su * 4;
      float4 v = *(const float4*)(xp + kb0 + kl);
      v.x = lrelu(v.x); v.y = lrelu(v.y); v.z = lrelu(v.z); v.w = lrelu(v.w);
      *(float4*)&sh[srow][kl] = v;
    }
    __syncthreads();
    const float* wb = W + (size_t)kb0 * JD + j0;
#pragma unroll 4
    for (int qq = 0; qq < KT2 / 4; ++qq) {
      float2 w0 = *(const float2*)(wb + (size_t)(qq * 4 + 0) * JD);
      float2 w1 = *(const float2*)(wb + (size_t)(qq * 4 + 1) * JD);
      float2 w2 = *(const float2*)(wb + (size_t)(qq * 4 + 2) * JD);
      float2 w3 = *(const float2*)(wb + (size_t)(qq * 4 + 3) * JD);
#pragma unroll
      for (int i = 0; i < 4; ++i) {
        float4 m = *(const float4*)&sh[rg * 4 + i][qq * 4];  // wave-uniform broadcast
        acc[i][0] = fmaf(m.x, w0.x, acc[i][0]);
        acc[i][0] = fmaf(m.y, w1.x, acc[i][0]);
        acc[i][0] = fmaf(m.z, w2.x, acc[i][0]);
        acc[i][0] = fmaf(m.w, w3.x, acc[i][0]);
        acc[i][1] = fmaf(m.x, w0.y, acc[i][1]);
        acc[i][1] = fmaf(m.y, w1.y, acc[i][1]);
        acc[i][1] = fmaf(m.z, w2.y, acc[i][1]);
        acc[i][1] = fmaf(m.w, w3.y, acc[i][1]);
      }
    }
  }
  float b0 = b[j0], b1v = b[j0 + 1];
#pragma unroll
  for (int i = 0; i < 4; ++i) {
    size_t row = (size_t)(m0 + rg * 4 + i);
    Y[row * JD + j0] = lrelu(acc[i][0] + b0);
    Y[row * JD + j0 + 1] = lrelu(acc[i][1] + b1v);
  }
}

// ---------------- mlp2 + layer3 fused: out = sigmoid( lrelu(z1@W2+b2) @ W3 + b3 )
// grid (256), 256 thr. Block: rows [bx*4,+4), all 256 cols (1 col/thread).
// Full occupancy (256 blocks, was 128) + epilogue block-reduction kills the
// z2 round-trip and the layer3 launch.
__global__ __launch_bounds__(256) void mlp2l3_kernel(
    const float* __restrict__ X, const float* __restrict__ W,
    const float* __restrict__ b, const float* __restrict__ W3,
    const float* __restrict__ b3, float* __restrict__ out) {
  constexpr int KD = TWOH, JD = HID, KT2 = 256;
  __shared__ float sh[4][KT2];
  __shared__ float red[4][4];  // [row][wave]
  int tid = threadIdx.x;
  int j = tid;
  int m0 = blockIdx.x * 4;
  int srow = tid >> 6, su = tid & 63;
  const float* xp = X + (size_t)(m0 + srow) * KD;
  float acc[4] = {0.f, 0.f, 0.f, 0.f};
  for (int kb0 = 0; kb0 < KD; kb0 += KT2) {
    __syncthreads();
    {
      float4 v = *(const float4*)(xp + kb0 + su * 4);
      *(float4*)&sh[srow][su * 4] = v;  // z1 already post-activation
    }
    __syncthreads();
    const float* wb = W + (size_t)kb0 * JD + j;
#pragma unroll 4
    for (int qq = 0; qq < KT2 / 4; ++qq) {
      float w0 = wb[(size_t)(qq * 4 + 0) * JD];
      float w1 = wb[(size_t)(qq * 4 + 1) * JD];
      float w2 = wb[(size_t)(qq * 4 + 2) * JD];
      float w3 = wb[(size_t)(qq * 4 + 3) * JD];
#pragma unroll
      for (int i = 0; i < 4; ++i) {
        float4 m = *(const float4*)&sh[i][qq * 4];  // wave-uniform broadcast
        acc[i] = fmaf(m.x, w0, acc[i]);
        acc[i] = fmaf(m.y, w1, acc[i]);
        acc[i] = fmaf(m.z, w2, acc[i]);
        acc[i] = fmaf(m.w, w3, acc[i]);
      }
    }
  }
  // epilogue: z2[row][j] = lrelu(acc[i]+b[j]); out[row] = sigmoid(z2 . W3 + b3)
  float bb = b[j];
  float w3j = W3[j];
  int wave = tid >> 6, lane = tid & 63;
#pragma unroll
  for (int i = 0; i < 4; ++i) {
    float d = lrelu(acc[i] + bb) * w3j;
#pragma unroll
    for (int off = 32; off; off >>= 1) d += __shfl_down(d, off);
    if (lane == 0) red[i][wave] = d;
  }
  __syncthreads();
  if (tid < 4) {
    float d = red[tid][0] + red[tid][1] + red[tid][2] + red[tid][3];
    out[m0 + tid] = 1.f / (1.f + expf(-(d + b3[0])));
  }
}

extern "C" void kernel_launch(void* const* d_in, const int* in_sizes, int n_in,
                              void* d_out, int out_size, void* d_ws, size_t ws_size,
                              hipStream_t stream) {
  const float* mazes = (const float*)d_in[0];
  const int* orders = (const int*)d_in[1];
  const float* embed = (const float*)d_in[2];
  const float* W_in = (const float*)d_in[3];
  const float* b_in = (const float*)d_in[4];
  const float* W1 = (const float*)d_in[5];
  const float* b1 = (const float*)d_in[6];
  const float* W2 = (const float*)d_in[7];
  const float* b2 = (const float*)d_in[8];
  const float* W3 = (const float*)d_in[9];
  const float* b3 = (const float*)d_in[10];
  float* out = (float*)d_out;

  char* ws = (char*)d_ws;
  int* counts = (int*)ws;       // 7 ints
  int* bases = counts + 8;      // 7 ints
  int* list = counts + 16;      // 1024 ints
  float* hinit = (float*)(ws + 64 * 1024);                     // 7*1024 f32
  float* h = (float*)(ws + 128 * 1024);                        // 1024*1024 f32 (4 MB)
  float* z1 = (float*)(ws + 128 * 1024 + 4 * 1024 * 1024);     // 1024*512 f32 (2 MB)
  unsigned short* Ab = (unsigned short*)(ws + 128 * 1024 + 8 * 1024 * 1024);  // 17.5 MB

  prep_kernel<<<1 + NEXP, 1024, 0, stream>>>(orders, counts, bases, list,
                                             embed, W_in, b_in, hinit);
  gather_hb_kernel<<<NEXP * MROWS + BATCH, 256, 0, stream>>>(
      mazes, counts, bases, list, Ab, orders, hinit, h);
  layerin_mfma<<<dim3(49, 8, 2), 256, 0, stream>>>(Ab, W_in, counts, bases, list, h);
  mlp1_kernel<<<dim3(2, 128), 256, 0, stream>>>(h, W1, b1, z1);
  mlp2l3_kernel<<<256, 256, 0, stream>>>(z1, W2, b2, W3, b3, out);
}

// Round 2
// 699.373 us; speedup vs baseline: 1.1509x; 1.0187x over previous
//
#include <hip/hip_runtime.h>
#include <cstdint>
#include <cstddef>

#define NEXP 7
#define EMBED_DIM 16
#define FOURH 1024
#define TWOH 512
#define HID 256
#define S_MAX 16641
#define D_IN (S_MAX + EMBED_DIM)
#define BATCH 1024
#define MTILE 192
#define MROWS 384  // 2 m-tiles of insurance capacity per expert

__constant__ int d_SIZES[NEXP] = {9, 25, 81, 289, 1089, 4225, 16641};
__constant__ int d_KPAD[NEXP] = {64, 64, 128, 320, 1152, 4288, 16704};
__constant__ int d_AOFF[NEXP] = {0, 64, 128, 256, 576, 1728, 6016};  // cum KPAD
// ceil(KPAD/512) = {1,1,1,1,3,9,33}; prefix:
__constant__ int d_KCOFF[NEXP + 1] = {0, 1, 2, 3, 4, 7, 16, 49};

typedef short bf16x8 __attribute__((ext_vector_type(8)));
typedef float f32x4 __attribute__((ext_vector_type(4)));

__device__ __forceinline__ float lrelu(float x) { return x > 0.f ? x : 0.2f * x; }

__device__ __forceinline__ unsigned short f2bf(float x) {
  union { float f; unsigned u; } v;
  v.f = x;
  unsigned r = v.u + 0x7FFFu + ((v.u >> 16) & 1u);  // RNE
  return (unsigned short)(r >> 16);
}

// hardware RNE f32->bf16 (compiler packs pairs into v_cvt_pk_bf16_f32)
__device__ __forceinline__ short f2bfs(float x) {
  union { __bf16 b; short s; } u;
  u.b = (__bf16)x;
  return u.s;
}

// ---------------- fused: bucket samples (block 0) + per-expert embed/bias init
// (blocks 1..7). Both roles independent; fusion removes one serialized launch.
__global__ __launch_bounds__(1024) void prep_kernel(
    const int* __restrict__ orders, int* __restrict__ counts,
    int* __restrict__ bases, int* __restrict__ list,
    const float* __restrict__ embed, const float* __restrict__ W_in,
    const float* __restrict__ b_in, float* __restrict__ hinit) {
  __shared__ int c[NEXP], p[NEXP];
  int t = threadIdx.x;
  if (blockIdx.x == 0) {
    // ---- bucket ----
    if (t < NEXP) c[t] = 0;
    __syncthreads();
    int o = orders[t];
    atomicAdd(&c[o], 1);
    __syncthreads();
    if (t == 0) {
      int s = 0;
      for (int i = 0; i < NEXP; ++i) { p[i] = s; s += c[i]; }
    }
    __syncthreads();
    if (t < NEXP) { counts[t] = c[t]; bases[t] = p[t]; }
    __syncthreads();
    int pos = atomicAdd(&p[o], 1);
    list[pos] = t;
  } else {
    // ---- hinit: hinit[o][j] = b_in[o][j] + embed[o] . W_in[o][S_MAX:][j] ----
    int o = blockIdx.x - 1;
    float a = b_in[o * FOURH + t];
    const float* wr = W_in + (size_t)o * D_IN * FOURH + (size_t)S_MAX * FOURH + t;
#pragma unroll
    for (int e = 0; e < EMBED_DIM; ++e)
      a = fmaf(embed[o * EMBED_DIM + e], wr[(size_t)e * FOURH], a);
    hinit[o * FOURH + t] = a;
  }
}

// ---------------- fused: gather+convert mazes into bucketed padded Ab (blocks
// [0, NEXP*MROWS)) + broadcast hinit into h by order (blocks [NEXP*MROWS, +1024))
// Insurance rows (m >= n) are NOT zeroed: layerin's epilogue guard discards
// every output that depends on them (MFMA rows are independent), so poison
// in those rows is harmless. Saves ~10 MB of zero-fill writes.
__global__ __launch_bounds__(256) void gather_hb_kernel(
    const float* __restrict__ mazes, const int* __restrict__ counts,
    const int* __restrict__ bases, const int* __restrict__ list,
    unsigned short* __restrict__ Ab, const int* __restrict__ orders,
    const float* __restrict__ hinit, float* __restrict__ h) {
  int bx = blockIdx.x;
  if (bx >= NEXP * MROWS) {
    // ---- h broadcast ----
    int b = bx - NEXP * MROWS;
    int o = orders[b];
    const float4* src = (const float4*)(hinit + (size_t)o * FOURH);
    float4* dst = (float4*)(h + (size_t)b * FOURH);
    dst[threadIdx.x] = src[threadIdx.x];
    return;
  }
  // ---- gather ----
  int o = bx / MROWS;
  int m = bx % MROWS;
  int n = counts[o];
  if (m >= n) return;  // garbage rows are discarded downstream
  int so = d_SIZES[o];
  int Kp = d_KPAD[o];
  const float* src = mazes + (size_t)list[bases[o] + m] * S_MAX;
  unsigned short* dst = Ab + (size_t)d_AOFF[o] * MROWS + (size_t)m * Kp;
  int nk8 = Kp >> 3;
  for (int k8 = threadIdx.x; k8 < nk8; k8 += 256) {
    int k = k8 * 8;
    union { unsigned short u[8]; uint4 v; } pk;
#pragma unroll
    for (int e = 0; e < 8; ++e) {
      float val = ((k + e) < so) ? src[k + e] : 0.f;
      pk.u[e] = f2bf(val);
    }
    *(uint4*)(dst + k) = pk.v;
  }
}

// ---------------- layer-in grouped GEMM via bf16 MFMA ----------------
// grid: x = 49 (o,kc) chunk instances, y = 8 n-tiles of 128, z = 2 m-tiles of 192.
// block: 256 thr = 4 waves; wave w covers cols [y*128 + w*32, +32) as 2 n-subtiles.
__global__ __launch_bounds__(256, 2) void layerin_mfma(
    const unsigned short* __restrict__ Ab, const float* __restrict__ W_in,
    const int* __restrict__ counts, const int* __restrict__ bases,
    const int* __restrict__ list, float* __restrict__ h) {
  int bx = blockIdx.x;
  int o = 0;
#pragma unroll
  for (int t = 1; t < NEXP; ++t)
    if (bx >= d_KCOFF[t]) o = t;
  int kc = bx - d_KCOFF[o];
  int n = counts[o];
  int m_base = blockIdx.z * MTILE;
  if (m_base >= n) return;  // insurance tile unused almost always

  __shared__ unsigned short sA[8 * 194 * 8];  // [kg][m pad 194][8] bf16
  __shared__ int sid[MTILE];

  int tid = threadIdx.x;
  int wave = tid >> 6, lane = tid & 63;
  int q = lane >> 4, l16 = lane & 15;

  if (tid < MTILE) sid[tid] = (m_base + tid < n) ? list[bases[o] + m_base + tid] : 0;

  int so = d_SIZES[o];
  int Kp = d_KPAD[o];
  int klo = kc * 512;
  int klen = min(512, Kp - klo);  // multiple of 64

  int n0 = blockIdx.y * 128 + wave * 32;
  const float* Wc = W_in + (size_t)o * D_IN * FOURH + n0 + l16;
  const unsigned short* Abase =
      Ab + (size_t)d_AOFF[o] * MROWS + (size_t)m_base * Kp + klo;

  f32x4 acc[12][2];
#pragma unroll
  for (int mt = 0; mt < 12; ++mt) {
    acc[mt][0] = (f32x4)0.f;
    acc[mt][1] = (f32x4)0.f;
  }

  int kg = tid & 7;        // stage: k-group
  int mrow = tid >> 3;     // stage: row within round (32 rows/round)

  for (int ks = 0; ks < klen; ks += 64) {
    __syncthreads();
#pragma unroll
    for (int r = 0; r < 6; ++r) {
      int m = r * 32 + mrow;
      uint4 v = *(const uint4*)(Abase + (size_t)m * Kp + ks + kg * 8);
      *(uint4*)&sA[((kg * 194 + m) << 3)] = v;
    }
    __syncthreads();
#pragma unroll
    for (int st = 0; st < 2; ++st) {
      int kb = klo + ks + st * 32 + q * 8;
      bf16x8 bf0, bf1;
#pragma unroll
      for (int j = 0; j < 8; ++j) {
        int kj = kb + j;
        if (kj >= so) kj = so - 1;  // A is zero there; clamp keeps loads in-bounds
        float w0 = Wc[(size_t)kj * FOURH];
        float w1 = Wc[(size_t)kj * FOURH + 16];
        bf0[j] = f2bfs(w0);
        bf1[j] = f2bfs(w1);
      }
#pragma unroll
      for (int mt = 0; mt < 12; ++mt) {
        bf16x8 af = *(const bf16x8*)&sA[(((st * 4 + q) * 194 + mt * 16 + l16) << 3)];
        acc[mt][0] = __builtin_amdgcn_mfma_f32_16x16x32_bf16(af, bf0, acc[mt][0], 0, 0, 0);
        acc[mt][1] = __builtin_amdgcn_mfma_f32_16x16x32_bf16(af, bf1, acc[mt][1], 0, 0, 0);
      }
    }
  }

  int colA = n0 + l16, colB = n0 + 16 + l16;
#pragma unroll
  for (int mt = 0; mt < 12; ++mt) {
#pragma unroll
    for (int r = 0; r < 4; ++r) {
      int m = mt * 16 + q * 4 + r;
      if (m_base + m < n) {
        int s = sid[m];
        atomicAdd(&h[(size_t)s * FOURH + colA], acc[mt][0][r]);
        atomicAdd(&h[(size_t)s * FOURH + colB], acc[mt][1][r]);
      }
    }
  }
}

// ---------------- mlp1: z1 = lrelu( lrelu(h) @ W1 + b1 ) ----------------
// grid (2, 128), 256 thr. Block: cols [bx*256,+256), rows [by*8,+8).
// Thread: jt = tid&63 -> 4 consecutive cols (float4 W loads);
//         rg = tid>>6  -> 2 rows (rg == wave, so LDS reads are pure broadcast).
// 4 cols/thread -> 1 B of LDS per lane-FMA (was 2), LDS time ~13 -> ~7 us.
__global__ __launch_bounds__(256) void mlp1_kernel(
    const float* __restrict__ X, const float* __restrict__ W,
    const float* __restrict__ b, float* __restrict__ Y) {
  constexpr int KD = FOURH, JD = TWOH, KT2 = 256;
  __shared__ float sh[8][KT2];
  int tid = threadIdx.x;
  int jt = tid & 63, rg = tid >> 6;
  int j0 = blockIdx.x * 256 + jt * 4;
  int m0 = blockIdx.y * 8;
  int srow = tid >> 5, su = tid & 31;
  const float* xp = X + (size_t)(m0 + srow) * KD;
  f32x4 acc[2];
  acc[0] = (f32x4)0.f;
  acc[1] = (f32x4)0.f;
  for (int kb0 = 0; kb0 < KD; kb0 += KT2) {
    __syncthreads();
#pragma unroll
    for (int c = 0; c < 2; ++c) {
      int kl = c * 128 + su * 4;
      float4 v = *(const float4*)(xp + kb0 + kl);
      v.x = lrelu(v.x); v.y = lrelu(v.y); v.z = lrelu(v.z); v.w = lrelu(v.w);
      *(float4*)&sh[srow][kl] = v;
    }
    __syncthreads();
    const float* wb = W + (size_t)kb0 * JD + j0;
#pragma unroll 4
    for (int qq = 0; qq < KT2 / 4; ++qq) {
      f32x4 w0 = *(const f32x4*)(wb + (size_t)(qq * 4 + 0) * JD);
      f32x4 w1 = *(const f32x4*)(wb + (size_t)(qq * 4 + 1) * JD);
      f32x4 w2 = *(const f32x4*)(wb + (size_t)(qq * 4 + 2) * JD);
      f32x4 w3 = *(const f32x4*)(wb + (size_t)(qq * 4 + 3) * JD);
#pragma unroll
      for (int i = 0; i < 2; ++i) {
        f32x4 xv = *(const f32x4*)&sh[rg * 2 + i][qq * 4];  // wave-uniform broadcast
#pragma unroll
        for (int cc = 0; cc < 4; ++cc) {
          acc[i][cc] = fmaf(xv[0], w0[cc], acc[i][cc]);
          acc[i][cc] = fmaf(xv[1], w1[cc], acc[i][cc]);
          acc[i][cc] = fmaf(xv[2], w2[cc], acc[i][cc]);
          acc[i][cc] = fmaf(xv[3], w3[cc], acc[i][cc]);
        }
      }
    }
  }
  f32x4 bb = *(const f32x4*)&b[j0];
#pragma unroll
  for (int i = 0; i < 2; ++i) {
    size_t row = (size_t)(m0 + rg * 2 + i);
    f32x4 ov;
#pragma unroll
    for (int cc = 0; cc < 4; ++cc) ov[cc] = lrelu(acc[i][cc] + bb[cc]);
    *(f32x4*)&Y[row * JD + j0] = ov;
  }
}

// ---------------- mlp2 + layer3 fused: out = sigmoid( lrelu(z1@W2+b2) @ W3 + b3 )
// grid (256), 256 thr. Block: rows [bx*4,+4), 256 cols.
// Thread: jt = tid&127 -> 2 cols (float2 W loads); rg = tid>>7 -> 2 rows.
// 2 B LDS/FMA (was 4). Epilogue block-reduce: wave w covers cols of one
// 64-lane jt slice; rows rg*2+{0,1}; red[row][wave&1] pairs then tid<4 sums.
__global__ __launch_bounds__(256) void mlp2l3_kernel(
    const float* __restrict__ X, const float* __restrict__ W,
    const float* __restrict__ b, const float* __restrict__ W3,
    const float* __restrict__ b3, float* __restrict__ out) {
  constexpr int KD = TWOH, JD = HID, KT2 = 256;
  __shared__ float sh[4][KT2];
  __shared__ float red[4][2];  // [row][half]
  int tid = threadIdx.x;
  int jt = tid & 127, rg = tid >> 7;
  int j0 = jt * 2;
  int m0 = blockIdx.x * 4;
  int srow = tid >> 6, su = tid & 63;
  const float* xp = X + (size_t)(m0 + srow) * KD;
  float2 acc[2];
  acc[0] = {0.f, 0.f};
  acc[1] = {0.f, 0.f};
  for (int kb0 = 0; kb0 < KD; kb0 += KT2) {
    __syncthreads();
    {
      float4 v = *(const float4*)(xp + kb0 + su * 4);
      *(float4*)&sh[srow][su * 4] = v;  // z1 already post-activation
    }
    __syncthreads();
    const float* wb = W + (size_t)kb0 * JD + j0;
#pragma unroll 4
    for (int qq = 0; qq < KT2 / 4; ++qq) {
      float2 w0 = *(const float2*)(wb + (size_t)(qq * 4 + 0) * JD);
      float2 w1 = *(const float2*)(wb + (size_t)(qq * 4 + 1) * JD);
      float2 w2 = *(const float2*)(wb + (size_t)(qq * 4 + 2) * JD);
      float2 w3 = *(const float2*)(wb + (size_t)(qq * 4 + 3) * JD);
#pragma unroll
      for (int i = 0; i < 2; ++i) {
        f32x4 xv = *(const f32x4*)&sh[rg * 2 + i][qq * 4];  // wave-uniform broadcast
        acc[i].x = fmaf(xv[0], w0.x, acc[i].x);
        acc[i].x = fmaf(xv[1], w1.x, acc[i].x);
        acc[i].x = fmaf(xv[2], w2.x, acc[i].x);
        acc[i].x = fmaf(xv[3], w3.x, acc[i].x);
        acc[i].y = fmaf(xv[0], w0.y, acc[i].y);
        acc[i].y = fmaf(xv[1], w1.y, acc[i].y);
        acc[i].y = fmaf(xv[2], w2.y, acc[i].y);
        acc[i].y = fmaf(xv[3], w3.y, acc[i].y);
      }
    }
  }
  // epilogue: z2[row][j] = lrelu(acc+b[j]); out[row] = sigmoid(z2 . W3 + b3)
  float b0v = b[j0], b1v = b[j0 + 1];
  float w3a = W3[j0], w3b = W3[j0 + 1];
  int wave = tid >> 6, lane = tid & 63;
#pragma unroll
  for (int i = 0; i < 2; ++i) {
    float d = lrelu(acc[i].x + b0v) * w3a + lrelu(acc[i].y + b1v) * w3b;
#pragma unroll
    for (int off = 32; off; off >>= 1) d += __shfl_down(d, off);
    if (lane == 0) red[rg * 2 + i][wave & 1] = d;
  }
  __syncthreads();
  if (tid < 4) {
    float d = red[tid][0] + red[tid][1];
    out[m0 + tid] = 1.f / (1.f + expf(-(d + b3[0])));
  }
}

extern "C" void kernel_launch(void* const* d_in, const int* in_sizes, int n_in,
                              void* d_out, int out_size, void* d_ws, size_t ws_size,
                              hipStream_t stream) {
  const float* mazes = (const float*)d_in[0];
  const int* orders = (const int*)d_in[1];
  const float* embed = (const float*)d_in[2];
  const float* W_in = (const float*)d_in[3];
  const float* b_in = (const float*)d_in[4];
  const float* W1 = (const float*)d_in[5];
  const float* b1 = (const float*)d_in[6];
  const float* W2 = (const float*)d_in[7];
  const float* b2 = (const float*)d_in[8];
  const float* W3 = (const float*)d_in[9];
  const float* b3 = (const float*)d_in[10];
  float* out = (float*)d_out;

  char* ws = (char*)d_ws;
  int* counts = (int*)ws;       // 7 ints
  int* bases = counts + 8;      // 7 ints
  int* list = counts + 16;      // 1024 ints
  float* hinit = (float*)(ws + 64 * 1024);                     // 7*1024 f32
  float* h = (float*)(ws + 128 * 1024);                        // 1024*1024 f32 (4 MB)
  float* z1 = (float*)(ws + 128 * 1024 + 4 * 1024 * 1024);     // 1024*512 f32 (2 MB)
  unsigned short* Ab = (unsigned short*)(ws + 128 * 1024 + 8 * 1024 * 1024);  // 17.5 MB

  prep_kernel<<<1 + NEXP, 1024, 0, stream>>>(orders, counts, bases, list,
                                             embed, W_in, b_in, hinit);
  gather_hb_kernel<<<NEXP * MROWS + BATCH, 256, 0, stream>>>(
      mazes, counts, bases, list, Ab, orders, hinit, h);
  layerin_mfma<<<dim3(49, 8, 2), 256, 0, stream>>>(Ab, W_in, counts, bases, list, h);
  mlp1_kernel<<<dim3(2, 128), 256, 0, stream>>>(h, W1, b1, z1);
  mlp2l3_kernel<<<256, 256, 0, stream>>>(z1, W2, b2, W3, b3, out);
}